// Round 1
// baseline (5236.371 us; speedup 1.0000x reference)
//
#include <hip/hip_runtime.h>

// Problem constants
#define T_STEPS 128
#define BATCH   64
#define VOCAB   8192
#define HID     2048
#define WROW    (VOCAB + HID)   // 10240, hidden_w row length

typedef __bf16 bf16_t;
typedef __bf16 bf16x8 __attribute__((ext_vector_type(8)));
typedef float  f32x4  __attribute__((ext_vector_type(4)));

// ---------------------------------------------------------------------------
// Zero the initial state block (bf16 zeros)
__global__ void zero_bf16(bf16_t* __restrict__ p, int n) {
    int i = blockIdx.x * blockDim.x + threadIdx.x;
    if (i < n) p[i] = (bf16_t)0.0f;
}

// ---------------------------------------------------------------------------
// Convert W_hh = hidden_w[:, V:] (2048x2048 fp32) -> bf16, row-major [h][j]
__global__ void conv_whh(const float* __restrict__ hw, bf16_t* __restrict__ whh) {
    int idx = blockIdx.x * 256 + threadIdx.x;   // 0 .. 2048*2048/4-1
    int i4 = idx * 4;
    int h = i4 >> 11;        // /2048
    int j = i4 & 2047;
    float4 w = *(const float4*)(hw + (size_t)h * WROW + VOCAB + j);
    union { bf16_t b[4]; uint2 u; } t;
    t.b[0] = (bf16_t)w.x; t.b[1] = (bf16_t)w.y; t.b[2] = (bf16_t)w.z; t.b[3] = (bf16_t)w.w;
    *(uint2*)(whh + (size_t)h * HID + j) = t.u;
}

// Convert output_w (8192x2048 fp32, contiguous) -> bf16
__global__ void conv_wout(const float* __restrict__ wo, bf16_t* __restrict__ wob) {
    size_t i4 = ((size_t)blockIdx.x * 256 + threadIdx.x) * 4;
    float4 w = *(const float4*)(wo + i4);
    union { bf16_t b[4]; uint2 u; } t;
    t.b[0] = (bf16_t)w.x; t.b[1] = (bf16_t)w.y; t.b[2] = (bf16_t)w.z; t.b[3] = (bf16_t)w.w;
    *(uint2*)(wob + i4) = t.u;
}

// Transpose+convert embedding block: wembT[v][h] = hidden_w[h][v], bf16
// grid (V/32, H/32), block (32, 8)
__global__ void trans_emb(const float* __restrict__ hw, bf16_t* __restrict__ wt) {
    __shared__ float tile[32][33];
    int tx = threadIdx.x, ty = threadIdx.y;
    int v0 = blockIdx.x * 32, h0 = blockIdx.y * 32;
#pragma unroll
    for (int i = 0; i < 4; i++)
        tile[ty + i * 8][tx] = hw[(size_t)(h0 + ty + i * 8) * WROW + v0 + tx];
    __syncthreads();
#pragma unroll
    for (int i = 0; i < 4; i++)
        wt[(size_t)(v0 + ty + i * 8) * HID + h0 + tx] = (bf16_t)tile[tx][ty + i * 8];
}

// ---------------------------------------------------------------------------
// One recurrence step: snext = tanh(sprev @ Whh^T + emb(tok) + bias)
// M=64 (batch), N=2048 (hid), K=2048. 16 blocks (BN=128), 256 thr, BK=64.
// Wave tile 64x32: 4 m-tiles x 2 n-tiles of 16x16x32 MFMA.
// LDS rows padded to 72 bf16 (9 uint4) to avoid bank conflicts.
__launch_bounds__(256)
__global__ void rnn_step(const bf16_t* __restrict__ sprev,   // 64 x 2048
                         bf16_t* __restrict__ snext,         // 64 x 2048
                         const bf16_t* __restrict__ whh,     // 2048 x 2048 [h][j]
                         const bf16_t* __restrict__ wembT,   // 8192 x 2048 [v][h]
                         const float* __restrict__ hb,       // 2048
                         const int* __restrict__ toks,       // T*B
                         int t, float* __restrict__ fin) {
    __shared__ uint4 AsU[2][64 * 9];
    __shared__ uint4 BsU[2][128 * 9];
    const int tid = threadIdx.x;
    const int w = tid >> 6, lane = tid & 63;
    const int q = lane >> 4, l15 = lane & 15;
    const int h0 = blockIdx.x * 128;

    const uint4* gA = (const uint4*)sprev;   // row stride 256 uint4 (2048 bf16)
    const uint4* gB = (const uint4*)whh;

    f32x4 acc[4][2];
#pragma unroll
    for (int mt = 0; mt < 4; mt++)
#pragma unroll
        for (int nt = 0; nt < 2; nt++)
            acc[mt][nt] = (f32x4){0.f, 0.f, 0.f, 0.f};

    uint4 pa[2], pb[4];
    // prefetch chunk 0 (k0 = 0): A is 64 rows x 8 uint4, B is 128 rows x 8 uint4
#pragma unroll
    for (int i = 0; i < 2; i++) {
        int v = tid + 256 * i;
        pa[i] = gA[(v >> 3) * 256 + (v & 7)];
    }
#pragma unroll
    for (int i = 0; i < 4; i++) {
        int v = tid + 256 * i;
        pb[i] = gB[(size_t)(h0 + (v >> 3)) * 256 + (v & 7)];
    }
#pragma unroll
    for (int i = 0; i < 2; i++) {
        int v = tid + 256 * i;
        AsU[0][(v >> 3) * 9 + (v & 7)] = pa[i];
    }
#pragma unroll
    for (int i = 0; i < 4; i++) {
        int v = tid + 256 * i;
        BsU[0][(v >> 3) * 9 + (v & 7)] = pb[i];
    }
    __syncthreads();

    for (int it = 0; it < 32; ++it) {
        int cur = it & 1;
        if (it < 31) {
            int k0v = (it + 1) * 8;
#pragma unroll
            for (int i = 0; i < 2; i++) {
                int v = tid + 256 * i;
                pa[i] = gA[(v >> 3) * 256 + k0v + (v & 7)];
            }
#pragma unroll
            for (int i = 0; i < 4; i++) {
                int v = tid + 256 * i;
                pb[i] = gB[(size_t)(h0 + (v >> 3)) * 256 + k0v + (v & 7)];
            }
        }
        bf16x8 af[2][4], bfr[2][2];
#pragma unroll
        for (int s = 0; s < 2; s++) {
#pragma unroll
            for (int mt = 0; mt < 4; mt++)
                af[s][mt] = *(const bf16x8*)&AsU[cur][(mt * 16 + l15) * 9 + s * 4 + q];
#pragma unroll
            for (int nt = 0; nt < 2; nt++)
                bfr[s][nt] = *(const bf16x8*)&BsU[cur][(w * 32 + nt * 16 + l15) * 9 + s * 4 + q];
        }
#pragma unroll
        for (int s = 0; s < 2; s++)
#pragma unroll
            for (int mt = 0; mt < 4; mt++)
#pragma unroll
                for (int nt = 0; nt < 2; nt++)
                    acc[mt][nt] = __builtin_amdgcn_mfma_f32_16x16x32_bf16(
                        af[s][mt], bfr[s][nt], acc[mt][nt], 0, 0, 0);
        if (it < 31) {
            int nxt = cur ^ 1;
#pragma unroll
            for (int i = 0; i < 2; i++) {
                int v = tid + 256 * i;
                AsU[nxt][(v >> 3) * 9 + (v & 7)] = pa[i];
            }
#pragma unroll
            for (int i = 0; i < 4; i++) {
                int v = tid + 256 * i;
                BsU[nxt][(v >> 3) * 9 + (v & 7)] = pb[i];
            }
        }
        __syncthreads();
    }

    // epilogue: C/D layout col = lane&15, row = (lane>>4)*4 + reg
#pragma unroll
    for (int mt = 0; mt < 4; mt++) {
#pragma unroll
        for (int nt = 0; nt < 2; nt++) {
            int h = h0 + w * 32 + nt * 16 + l15;
            float bias = hb[h];
#pragma unroll
            for (int i = 0; i < 4; i++) {
                int b = mt * 16 + q * 4 + i;
                int tok = toks[t * BATCH + b];
                float pre = acc[mt][nt][i] + (float)wembT[(size_t)tok * HID + h] + bias;
                float s = tanhf(pre);
                snext[(size_t)b * HID + h] = (bf16_t)s;
                if (fin) fin[(size_t)b * HID + h] = s;
            }
        }
    }
}

// ---------------------------------------------------------------------------
// Output GEMM: out[i][v] = sum_h states[i][h] * Wout[v][h] + bias[v]
// M=8192, N=8192, K=2048. BM=BN=128, BK=32, 256 thr = 2x2 waves of 64x64.
__launch_bounds__(256)
__global__ void out_gemm(const bf16_t* __restrict__ A,    // 8192 x 2048
                         const bf16_t* __restrict__ Bw,   // 8192 x 2048 [v][h]
                         const float* __restrict__ bias,  // 8192
                         float* __restrict__ out) {       // 8192 x 8192
    __shared__ uint4 AsU[2][128 * 5];
    __shared__ uint4 BsU[2][128 * 5];
    const int tid = threadIdx.x;
    const int wv = tid >> 6, lane = tid & 63;
    const int wm = wv >> 1, wn = wv & 1;
    const int q = lane >> 4, l15 = lane & 15;
    const int bm = blockIdx.y, bn = blockIdx.x;

    const uint4* gA = (const uint4*)A + (size_t)bm * 128 * 256;
    const uint4* gB = (const uint4*)Bw + (size_t)bn * 128 * 256;

    f32x4 acc[4][4];
#pragma unroll
    for (int mt = 0; mt < 4; mt++)
#pragma unroll
        for (int nt = 0; nt < 4; nt++)
            acc[mt][nt] = (f32x4){0.f, 0.f, 0.f, 0.f};

    uint4 pa[2], pb[2];
    // chunk layout: 128 rows x 4 uint4 (BK=32) per matrix = 512 vec; 2/thread
#pragma unroll
    for (int i = 0; i < 2; i++) {
        int v = tid + 256 * i;
        pa[i] = gA[(v >> 2) * 256 + (v & 3)];
        pb[i] = gB[(v >> 2) * 256 + (v & 3)];
    }
#pragma unroll
    for (int i = 0; i < 2; i++) {
        int v = tid + 256 * i;
        AsU[0][(v >> 2) * 5 + (v & 3)] = pa[i];
        BsU[0][(v >> 2) * 5 + (v & 3)] = pb[i];
    }
    __syncthreads();

    for (int it = 0; it < 64; ++it) {
        int cur = it & 1;
        if (it < 63) {
            int k0v = (it + 1) * 4;
#pragma unroll
            for (int i = 0; i < 2; i++) {
                int v = tid + 256 * i;
                pa[i] = gA[(v >> 2) * 256 + k0v + (v & 3)];
                pb[i] = gB[(v >> 2) * 256 + k0v + (v & 3)];
            }
        }
        bf16x8 af[4], bfr[4];
#pragma unroll
        for (int mt = 0; mt < 4; mt++)
            af[mt] = *(const bf16x8*)&AsU[cur][(wm * 64 + mt * 16 + l15) * 5 + q];
#pragma unroll
        for (int nt = 0; nt < 4; nt++)
            bfr[nt] = *(const bf16x8*)&BsU[cur][(wn * 64 + nt * 16 + l15) * 5 + q];
#pragma unroll
        for (int mt = 0; mt < 4; mt++)
#pragma unroll
            for (int nt = 0; nt < 4; nt++)
                acc[mt][nt] = __builtin_amdgcn_mfma_f32_16x16x32_bf16(
                    af[mt], bfr[nt], acc[mt][nt], 0, 0, 0);
        if (it < 63) {
            int nxt = cur ^ 1;
#pragma unroll
            for (int i = 0; i < 2; i++) {
                int v = tid + 256 * i;
                AsU[nxt][(v >> 2) * 5 + (v & 3)] = pa[i];
                BsU[nxt][(v >> 2) * 5 + (v & 3)] = pb[i];
            }
        }
        __syncthreads();
    }

#pragma unroll
    for (int nt = 0; nt < 4; nt++) {
        int col = bn * 128 + wn * 64 + nt * 16 + l15;
        float bv = bias[col];
#pragma unroll
        for (int mt = 0; mt < 4; mt++) {
#pragma unroll
            for (int i = 0; i < 4; i++) {
                int row = bm * 128 + wm * 64 + mt * 16 + q * 4 + i;
                out[(size_t)row * 8192 + col] = acc[mt][nt][i] + bv;
            }
        }
    }
}

// ---------------------------------------------------------------------------
extern "C" void kernel_launch(void* const* d_in, const int* in_sizes, int n_in,
                              void* d_out, int out_size, void* d_ws, size_t ws_size,
                              hipStream_t stream) {
    const int*   toks = (const int*)d_in[0];     // (T, B) token ids
    const float* hw   = (const float*)d_in[1];   // (H, V+H)
    const float* hb   = (const float*)d_in[2];   // (H,)
    const float* wo   = (const float*)d_in[3];   // (V, H)
    const float* ob   = (const float*)d_in[4];   // (V,)
    float* out = (float*)d_out;                  // T*B*V outputs then B*H final state

    // Workspace layout (bytes):
    //   states : (T+1)*B*H bf16 = 33,816,576   (block 0 = zero initial state)
    //   whh    : H*H bf16       =  8,388,608
    //   woutb  : V*H bf16       = 33,554,432
    //   wembT  : V*H bf16       = 33,554,432   total ~109.3 MB
    char* ws = (char*)d_ws;
    bf16_t* states = (bf16_t*)ws;
    bf16_t* whh    = (bf16_t*)(ws + 33816576ULL);
    bf16_t* woutb  = (bf16_t*)(ws + 33816576ULL + 8388608ULL);
    bf16_t* wembT  = (bf16_t*)(ws + 33816576ULL + 8388608ULL + 33554432ULL);

    zero_bf16<<<512, 256, 0, stream>>>(states, BATCH * HID);
    conv_whh<<<(HID * HID / 4) / 256, 256, 0, stream>>>(hw, whh);
    conv_wout<<<(VOCAB * HID / 4) / 256, 256, 0, stream>>>(wo, woutb);
    trans_emb<<<dim3(VOCAB / 32, HID / 32), dim3(32, 8), 0, stream>>>(hw, wembT);

    for (int t = 0; t < T_STEPS; ++t) {
        float* fin = (t == T_STEPS - 1)
                   ? (out + (size_t)T_STEPS * BATCH * VOCAB) : nullptr;
        rnn_step<<<16, 256, 0, stream>>>(
            states + (size_t)t * BATCH * HID,
            states + (size_t)(t + 1) * BATCH * HID,
            whh, wembT, hb, toks, t, fin);
    }

    out_gemm<<<dim3(64, 64), 256, 0, stream>>>(
        states + (size_t)BATCH * HID, woutb, ob, out);
}

// Round 2
// 4643.068 us; speedup vs baseline: 1.1278x; 1.1278x over previous
//
#include <hip/hip_runtime.h>
#include <hip/hip_cooperative_groups.h>

namespace cg = cooperative_groups;

// Problem constants
#define T_STEPS 128
#define BATCH   64
#define VOCAB   8192
#define HID     2048
#define WROW    (VOCAB + HID)   // 10240, hidden_w row length
#define BH      (BATCH * HID)   // 131072, one state slab

typedef __bf16 bf16_t;
typedef __bf16 bf16x8 __attribute__((ext_vector_type(8)));
typedef float  f32x4  __attribute__((ext_vector_type(4)));

// ---------------------------------------------------------------------------
// Convert W_hh = hidden_w[:, V:] (2048x2048 fp32) -> bf16, row-major [h][j]
__global__ void conv_whh(const float* __restrict__ hw, bf16_t* __restrict__ whh) {
    int idx = blockIdx.x * 256 + threadIdx.x;
    int i4 = idx * 4;
    int h = i4 >> 11;
    int j = i4 & 2047;
    float4 w = *(const float4*)(hw + (size_t)h * WROW + VOCAB + j);
    union { bf16_t b[4]; uint2 u; } t;
    t.b[0] = (bf16_t)w.x; t.b[1] = (bf16_t)w.y; t.b[2] = (bf16_t)w.z; t.b[3] = (bf16_t)w.w;
    *(uint2*)(whh + (size_t)h * HID + j) = t.u;
}

// Convert output_w (8192x2048 fp32, contiguous) -> bf16
__global__ void conv_wout(const float* __restrict__ wo, bf16_t* __restrict__ wob) {
    size_t i4 = ((size_t)blockIdx.x * 256 + threadIdx.x) * 4;
    float4 w = *(const float4*)(wo + i4);
    union { bf16_t b[4]; uint2 u; } t;
    t.b[0] = (bf16_t)w.x; t.b[1] = (bf16_t)w.y; t.b[2] = (bf16_t)w.z; t.b[3] = (bf16_t)w.w;
    *(uint2*)(wob + i4) = t.u;
}

// Transpose+convert embedding block: wembT[v][h] = hidden_w[h][v], bf16
// grid (V/32, H/32), block (32, 8)
__global__ void trans_emb(const float* __restrict__ hw, bf16_t* __restrict__ wt) {
    __shared__ float tile[32][33];
    int tx = threadIdx.x, ty = threadIdx.y;
    int v0 = blockIdx.x * 32, h0 = blockIdx.y * 32;
#pragma unroll
    for (int i = 0; i < 4; i++)
        tile[ty + i * 8][tx] = hw[(size_t)(h0 + ty + i * 8) * WROW + v0 + tx];
    __syncthreads();
#pragma unroll
    for (int i = 0; i < 4; i++)
        wt[(size_t)(v0 + ty + i * 8) * HID + h0 + tx] = (bf16_t)tile[tx][ty + i * 8];
}

// ---------------------------------------------------------------------------
// Persistent cooperative recurrence kernel: all 128 steps in one launch.
// Grid 256 blocks x 512 threads. Block (bm,bn): bm = m-slice of 16 batch rows,
// bn = n-slice of 32 hidden cols. 8 waves split K (2048) -> 256 each.
// Whh slice lives in registers for the whole kernel (16 bf16x8 frags/lane).
// Step t: read state slab t (t>0), MFMA vs resident B, LDS K-reduction,
// fused emb+bias+tanh epilogue -> write slab t+1, grid.sync().
__launch_bounds__(512)
__global__ void rnn_persist(bf16_t* __restrict__ states,    // (T+1) slabs of 64x2048
                            const bf16_t* __restrict__ whh, // 2048 x 2048 [h][k]
                            const bf16_t* __restrict__ wembT,// 8192 x 2048 [v][h]
                            const float* __restrict__ hb,   // 2048
                            const int* __restrict__ toks,   // T*B
                            float* __restrict__ fin) {      // 64 x 2048 fp32
    cg::grid_group grid = cg::this_grid();
    __shared__ float part[8][512];                           // 16 KB

    const int tid = threadIdx.x;
    const int w = tid >> 6, lane = tid & 63;
    const int q = lane >> 4, l15 = lane & 15;
    const int bm = blockIdx.x & 3, bn = blockIdx.x >> 2;
    const int m0 = bm * 16, n0 = bn * 32;
    const int kb = w * 256;                                  // this wave's K base

    // Load persistent B fragments: B[n0+nt*16+l15][kb + kk*32 + q*8 .. +8]
    bf16x8 breg[2][8];
#pragma unroll
    for (int nt = 0; nt < 2; nt++)
#pragma unroll
        for (int kk = 0; kk < 8; kk++)
            breg[nt][kk] = *(const bf16x8*)(
                whh + (size_t)(n0 + nt * 16 + l15) * HID + kb + kk * 32 + q * 8);

    const int abase = (m0 + l15) * HID + kb + q * 8;         // lane's A offset
    const int r = tid >> 5, c = tid & 31;                    // epilogue output
    const int R = m0 + r, h = n0 + c;
    const float bias = hb[h];

    for (int t = 0; t < T_STEPS; ++t) {
        f32x4 acc0 = (f32x4){0.f, 0.f, 0.f, 0.f};
        f32x4 acc1 = (f32x4){0.f, 0.f, 0.f, 0.f};
        if (t > 0) {
            const bf16_t* sprev = states + (size_t)t * BH;
            bf16x8 areg[8];
#pragma unroll
            for (int kk = 0; kk < 8; kk++)
                areg[kk] = *(const bf16x8*)(sprev + abase + kk * 32);
#pragma unroll
            for (int kk = 0; kk < 8; kk++) {
                acc0 = __builtin_amdgcn_mfma_f32_16x16x32_bf16(areg[kk], breg[0][kk], acc0, 0, 0, 0);
                acc1 = __builtin_amdgcn_mfma_f32_16x16x32_bf16(areg[kk], breg[1][kk], acc1, 0, 0, 0);
            }
        }
        // write K-partials: C/D layout col = l15, row = q*4 + i
#pragma unroll
        for (int i = 0; i < 4; i++) {
            part[w][(q * 4 + i) * 32 + l15]      = acc0[i];
            part[w][(q * 4 + i) * 32 + 16 + l15] = acc1[i];
        }
        __syncthreads();
        // epilogue: one output element per thread
        {
            float s = 0.f;
#pragma unroll
            for (int ww = 0; ww < 8; ww++) s += part[ww][tid];
            int tok = toks[t * BATCH + R];
            float pre = s + (float)wembT[(size_t)tok * HID + h] + bias;
            float v = tanhf(pre);
            states[(size_t)(t + 1) * BH + R * HID + h] = (bf16_t)v;
            if (t == T_STEPS - 1) fin[R * HID + h] = v;
        }
        grid.sync();   // also orders part[] reuse (block-level barrier included)
    }
}

// ---------------------------------------------------------------------------
// Output GEMM: out[i][v] = sum_h states[i][h] * Wout[v][h] + bias[v]
// M=8192, N=8192, K=2048. BM=BN=128, BK=32, 256 thr = 2x2 waves of 64x64.
__launch_bounds__(256)
__global__ void out_gemm(const bf16_t* __restrict__ A,    // 8192 x 2048
                         const bf16_t* __restrict__ Bw,   // 8192 x 2048 [v][h]
                         const float* __restrict__ bias,  // 8192
                         float* __restrict__ out) {       // 8192 x 8192
    __shared__ uint4 AsU[2][128 * 5];
    __shared__ uint4 BsU[2][128 * 5];
    const int tid = threadIdx.x;
    const int wv = tid >> 6, lane = tid & 63;
    const int wm = wv >> 1, wn = wv & 1;
    const int q = lane >> 4, l15 = lane & 15;
    const int bm = blockIdx.y, bn = blockIdx.x;

    const uint4* gA = (const uint4*)A + (size_t)bm * 128 * 256;
    const uint4* gB = (const uint4*)Bw + (size_t)bn * 128 * 256;

    f32x4 acc[4][4];
#pragma unroll
    for (int mt = 0; mt < 4; mt++)
#pragma unroll
        for (int nt = 0; nt < 4; nt++)
            acc[mt][nt] = (f32x4){0.f, 0.f, 0.f, 0.f};

    uint4 pa[2], pb[2];
#pragma unroll
    for (int i = 0; i < 2; i++) {
        int v = tid + 256 * i;
        pa[i] = gA[(v >> 2) * 256 + (v & 3)];
        pb[i] = gB[(v >> 2) * 256 + (v & 3)];
    }
#pragma unroll
    for (int i = 0; i < 2; i++) {
        int v = tid + 256 * i;
        AsU[0][(v >> 2) * 5 + (v & 3)] = pa[i];
        BsU[0][(v >> 2) * 5 + (v & 3)] = pb[i];
    }
    __syncthreads();

    for (int it = 0; it < 64; ++it) {
        int cur = it & 1;
        if (it < 63) {
            int k0v = (it + 1) * 4;
#pragma unroll
            for (int i = 0; i < 2; i++) {
                int v = tid + 256 * i;
                pa[i] = gA[(v >> 2) * 256 + k0v + (v & 3)];
                pb[i] = gB[(v >> 2) * 256 + k0v + (v & 3)];
            }
        }
        bf16x8 af[4], bfr[4];
#pragma unroll
        for (int mt = 0; mt < 4; mt++)
            af[mt] = *(const bf16x8*)&AsU[cur][(wm * 64 + mt * 16 + l15) * 5 + q];
#pragma unroll
        for (int nt = 0; nt < 4; nt++)
            bfr[nt] = *(const bf16x8*)&BsU[cur][(wn * 64 + nt * 16 + l15) * 5 + q];
#pragma unroll
        for (int mt = 0; mt < 4; mt++)
#pragma unroll
            for (int nt = 0; nt < 4; nt++)
                acc[mt][nt] = __builtin_amdgcn_mfma_f32_16x16x32_bf16(
                    af[mt], bfr[nt], acc[mt][nt], 0, 0, 0);
        if (it < 63) {
            int nxt = cur ^ 1;
#pragma unroll
            for (int i = 0; i < 2; i++) {
                int v = tid + 256 * i;
                AsU[nxt][(v >> 2) * 5 + (v & 3)] = pa[i];
                BsU[nxt][(v >> 2) * 5 + (v & 3)] = pb[i];
            }
        }
        __syncthreads();
    }

#pragma unroll
    for (int nt = 0; nt < 4; nt++) {
        int col = bn * 128 + wn * 64 + nt * 16 + l15;
        float bv = bias[col];
#pragma unroll
        for (int mt = 0; mt < 4; mt++) {
#pragma unroll
            for (int i = 0; i < 4; i++) {
                int row = bm * 128 + wm * 64 + mt * 16 + q * 4 + i;
                out[(size_t)row * 8192 + col] = acc[mt][nt][i] + bv;
            }
        }
    }
}

// ---------------------------------------------------------------------------
extern "C" void kernel_launch(void* const* d_in, const int* in_sizes, int n_in,
                              void* d_out, int out_size, void* d_ws, size_t ws_size,
                              hipStream_t stream) {
    const int*   toks = (const int*)d_in[0];     // (T, B) token ids
    const float* hw   = (const float*)d_in[1];   // (H, V+H)
    const float* hb   = (const float*)d_in[2];   // (H,)
    const float* wo   = (const float*)d_in[3];   // (V, H)
    const float* ob   = (const float*)d_in[4];   // (V,)
    float* out = (float*)d_out;                  // T*B*V outputs then B*H final state

    // Workspace layout (bytes):
    //   states : (T+1)*B*H bf16 = 33,816,576   (slab 0 unused; step t writes t+1)
    //   whh    : H*H bf16       =  8,388,608
    //   woutb  : V*H bf16       = 33,554,432
    //   wembT  : V*H bf16       = 33,554,432   total ~109.3 MB
    char* ws = (char*)d_ws;
    bf16_t* states = (bf16_t*)ws;
    bf16_t* whh    = (bf16_t*)(ws + 33816576ULL);
    bf16_t* woutb  = (bf16_t*)(ws + 33816576ULL + 8388608ULL);
    bf16_t* wembT  = (bf16_t*)(ws + 33816576ULL + 8388608ULL + 33554432ULL);

    conv_whh<<<(HID * HID / 4) / 256, 256, 0, stream>>>(hw, whh);
    conv_wout<<<(VOCAB * HID / 4) / 256, 256, 0, stream>>>(wo, woutb);
    trans_emb<<<dim3(VOCAB / 32, HID / 32), dim3(32, 8), 0, stream>>>(hw, wembT);

    // Persistent cooperative recurrence: all 128 steps, Whh register-resident.
    float* fin = out + (size_t)T_STEPS * BATCH * VOCAB;
    void* args[] = { (void*)&states, (void*)&whh, (void*)&wembT,
                     (void*)&hb, (void*)&toks, (void*)&fin };
    hipLaunchCooperativeKernel((void*)rnn_persist, dim3(256), dim3(512),
                               args, 0, stream);

    out_gemm<<<dim3(64, 64), 256, 0, stream>>>(
        states + (size_t)BH, woutb, ob, out);
}